// Round 4
// baseline (167.562 us; speedup 1.0000x reference)
//
#include <hip/hip_runtime.h>

typedef unsigned int u32;
typedef int i32x4 __attribute__((ext_vector_type(4)));

// ws layout (bytes):
//   [0..3]      amax (float)
//   [64..1087]  256 partial maxima (float)
//   [2048..]    Wq: [1024 l][768 f] signed int8 (same layout as W_in)
#define WQ_OFF 2048

__device__ __forceinline__ void gld16(const void* g, void* l) {
    __builtin_amdgcn_global_load_lds(
        (const __attribute__((address_space(1))) void*)g,
        (__attribute__((address_space(3))) void*)l, 16, 0, 0);
}

// ---------------------------------------------------------------------------
// absmax two-stage tree (no atomics)
// ---------------------------------------------------------------------------
__global__ __launch_bounds__(256) void amax_stage1(const float* __restrict__ W,
                                                   float* __restrict__ part) {
    int t = blockIdx.x * 256 + threadIdx.x;
    float v = 0.0f;
#pragma unroll
    for (int k = 0; k < 12; ++k) v = fmaxf(v, fabsf(W[t + (k << 16)]));
#pragma unroll
    for (int d = 32; d >= 1; d >>= 1) v = fmaxf(v, __shfl_xor(v, d));
    __shared__ float sm[4];
    if ((threadIdx.x & 63) == 0) sm[threadIdx.x >> 6] = v;
    __syncthreads();
    if (threadIdx.x == 0)
        part[blockIdx.x] = fmaxf(fmaxf(sm[0], sm[1]), fmaxf(sm[2], sm[3]));
}

__global__ __launch_bounds__(256) void amax_stage2(const float* __restrict__ part,
                                                   float* __restrict__ amax) {
    float v = part[threadIdx.x];
#pragma unroll
    for (int d = 32; d >= 1; d >>= 1) v = fmaxf(v, __shfl_xor(v, d));
    __shared__ float sm[4];
    if ((threadIdx.x & 63) == 0) sm[threadIdx.x >> 6] = v;
    __syncthreads();
    if (threadIdx.x == 0)
        amax[0] = fmaxf(fmaxf(sm[0], sm[1]), fmaxf(sm[2], sm[3]));
}

// ---------------------------------------------------------------------------
// quantize W_in -> signed i8, same [1024][768] layout (pure elementwise)
// ---------------------------------------------------------------------------
__global__ __launch_bounds__(256) void quant_k(const float* __restrict__ W,
                                               const float* __restrict__ amax,
                                               u32* __restrict__ Wq4) {
    int i = blockIdx.x * 256 + threadIdx.x;     // dword index, 196608 total
    float s = 127.0f / amax[0];
    float4 v = ((const float4*)W)[i];
    int a0 = (int)rintf(v.x * s), a1 = (int)rintf(v.y * s);
    int a2 = (int)rintf(v.z * s), a3 = (int)rintf(v.w * s);
    Wq4[i] = (u32)(a0 & 0xFF) | ((u32)(a1 & 0xFF) << 8) |
             ((u32)(a2 & 0xFF) << 16) | ((u32)(a3 & 0xFF) << 24);
}

// ---------------------------------------------------------------------------
// Fused forward: 64 rows/block, 512 threads (8 waves = 4 row-strips x 2
// col-halves), i8 MFMA 16x16x64 over K=768, N chunked x128 with fused
// bucket-head epilogue. h is never materialized.
// ---------------------------------------------------------------------------
__global__ __launch_bounds__(512, 4) void nnue_fwd(
    const float* __restrict__ x,       // [B][768] values in {0,1}
    const signed char* __restrict__ Wq,// [1024][768] i8
    const float* __restrict__ amax,
    const float* __restrict__ b_in,    // [1024]
    const float* __restrict__ W_h,     // [8][1024]
    const float* __restrict__ b_h,     // [8]
    const float* __restrict__ W_psqt,  // [768]
    float* __restrict__ out) {         // [B]

    __shared__ __align__(16) unsigned char xs8[64 * 768];   // 48 KB, swizzled
    __shared__ __align__(16) signed char   bs8[128 * 64];   // 8 KB B slice
    __shared__ int   bmeta[64];
    __shared__ float pmeta[64];
    __shared__ float comb[64][2];

    const int t = threadIdx.x;

    // ---- phase 1: x -> i8 LDS; fused popcount->bucket and exact psqt ----
    {
        const int r = t >> 3, seg = t & 7;
        const size_t grow = (size_t)(blockIdx.x << 6) + r;
        const float4* xr = (const float4*)(x + grow * 768 + seg * 96);
        const float4* pq = (const float4*)(W_psqt + seg * 96);
        u32 csum = 0; float ps = 0.0f;
#define PKB(f) ((__float_as_uint(f.x) >> 29)        |                     \
                ((__float_as_uint(f.y) >> 29) << 8)  |                     \
                ((__float_as_uint(f.z) >> 29) << 16) |                     \
                ((__float_as_uint(f.w) >> 29) << 24))
#define DOT4(f, q) ps = fmaf(f.x, q.x, ps); ps = fmaf(f.y, q.y, ps);       \
                   ps = fmaf(f.z, q.z, ps); ps = fmaf(f.w, q.w, ps);
#pragma unroll
        for (int i = 0; i < 6; ++i) {
            float4 f0 = xr[i*4+0], f1 = xr[i*4+1], f2 = xr[i*4+2], f3 = xr[i*4+3];
            float4 q0 = pq[i*4+0], q1 = pq[i*4+1], q2 = pq[i*4+2], q3 = pq[i*4+3];
            u32 d0 = PKB(f0), d1 = PKB(f1), d2 = PKB(f2), d3 = PKB(f3);
            csum += d0 + d1 + d2 + d3;                  // byte lanes <= 24
            DOT4(f0, q0) DOT4(f1, q1) DOT4(f2, q2) DOT4(f3, q3)
            int j  = seg * 6 + i;                       // 16B chunk 0..47
            int js = (j & ~7) | ((j ^ (r & 7)) & 7);    // bank swizzle
            *(uint4*)(&xs8[r * 768 + js * 16]) = make_uint4(d0, d1, d2, d3);
        }
#undef DOT4
#undef PKB
        int cnt = (csum & 0xFF) + ((csum >> 8) & 0xFF) +
                  ((csum >> 16) & 0xFF) + ((csum >> 24) & 0xFF);
#pragma unroll
        for (int d = 1; d < 8; d <<= 1) {
            cnt += __shfl_xor(cnt, d);
            ps  += __shfl_xor(ps, d);
        }
        if (seg == 0) { bmeta[r] = (cnt - 1) >> 2; pmeta[r] = ps; }
    }
    __syncthreads();

    // ---- phase 2: MFMA main loop ----------------------------------------
    const int l = t & 63, w = t >> 6;
    const int strip = w >> 1, hf = w & 1;
    const int cr = l & 15, g = l >> 4;
    const int arow  = (strip << 4) + cr;        // A row this lane reads
    const int rbase = (strip << 4) + (g << 2);  // rows this lane accumulates

    const int b0 = bmeta[rbase + 0], b1 = bmeta[rbase + 1];
    const int b2 = bmeta[rbase + 2], b3 = bmeta[rbase + 3];
    const float* wh0 = W_h + (b0 << 10);
    const float* wh1 = W_h + (b1 << 10);
    const float* wh2 = W_h + (b2 << 10);
    const float* wh3 = W_h + (b3 << 10);

    const float sc = amax[0] * (1.0f / 127.0f);
    float rs0 = 0.f, rs1 = 0.f, rs2 = 0.f, rs3 = 0.f;

    const signed char* wq_base = Wq + (size_t)(t >> 2) * 768 + (t & 3) * 16;
    void* lds_dst = (void*)&bs8[w << 10];       // wave-uniform base
    const unsigned char* arp = &xs8[arow * 768];
    const signed char*   bpb = &bs8[(((hf << 6) + cr) << 6) + (g << 4)];

    for (int c = 0; c < 8; ++c) {
        i32x4 acc0 = {0,0,0,0}, acc1 = {0,0,0,0};
        i32x4 acc2 = {0,0,0,0}, acc3 = {0,0,0,0};
        const signed char* src_c = wq_base + (size_t)c * (128 * 768);
        for (int ks = 0; ks < 12; ++ks) {
            __syncthreads();                    // bs8 reads of ks-1 done
            gld16(src_c + (ks << 6), lds_dst);  // stage B slice (c, ks)
            __syncthreads();                    // vmcnt(0) drain + barrier
            int j  = (ks << 2) + g;
            int js = (j & ~7) | ((j ^ (arow & 7)) & 7);
            i32x4 af  = *(const i32x4*)(arp + (js << 4));
            i32x4 bf0 = *(const i32x4*)(bpb);
            i32x4 bf1 = *(const i32x4*)(bpb + 1024);
            i32x4 bf2 = *(const i32x4*)(bpb + 2048);
            i32x4 bf3 = *(const i32x4*)(bpb + 3072);
            acc0 = __builtin_amdgcn_mfma_i32_16x16x64_i8(af, bf0, acc0, 0, 0, 0);
            acc1 = __builtin_amdgcn_mfma_i32_16x16x64_i8(af, bf1, acc1, 0, 0, 0);
            acc2 = __builtin_amdgcn_mfma_i32_16x16x64_i8(af, bf2, acc2, 0, 0, 0);
            acc3 = __builtin_amdgcn_mfma_i32_16x16x64_i8(af, bf3, acc3, 0, 0, 0);
        }
        // fused epilogue for this N-chunk (registers + L1-hot globals only)
        const int colb = (c << 7) + (hf << 6) + cr;
#define EPI(acc, ti)                                                        \
        { int col = colb + ((ti) << 4);                                     \
          float bi = b_in[col];                                             \
          float h0 = fminf(fmaxf(fmaf((float)acc[0], sc, bi), 0.f), 1.f);   \
          float h1 = fminf(fmaxf(fmaf((float)acc[1], sc, bi), 0.f), 1.f);   \
          float h2 = fminf(fmaxf(fmaf((float)acc[2], sc, bi), 0.f), 1.f);   \
          float h3 = fminf(fmaxf(fmaf((float)acc[3], sc, bi), 0.f), 1.f);   \
          rs0 = fmaf(h0, wh0[col], rs0);                                    \
          rs1 = fmaf(h1, wh1[col], rs1);                                    \
          rs2 = fmaf(h2, wh2[col], rs2);                                    \
          rs3 = fmaf(h3, wh3[col], rs3); }
        EPI(acc0, 0) EPI(acc1, 1) EPI(acc2, 2) EPI(acc3, 3)
#undef EPI
    }

    // ---- reduce across the 16 cols each lane-group covers ---------------
#pragma unroll
    for (int d = 1; d < 16; d <<= 1) {
        rs0 += __shfl_xor(rs0, d); rs1 += __shfl_xor(rs1, d);
        rs2 += __shfl_xor(rs2, d); rs3 += __shfl_xor(rs3, d);
    }
    if (cr == 0) {
        comb[rbase + 0][hf] = rs0; comb[rbase + 1][hf] = rs1;
        comb[rbase + 2][hf] = rs2; comb[rbase + 3][hf] = rs3;
    }
    __syncthreads();
    if (t < 64) {
        out[(blockIdx.x << 6) + t] =
            comb[t][0] + comb[t][1] + pmeta[t] + b_h[bmeta[t]];
    }
}

extern "C" void kernel_launch(void* const* d_in, const int* in_sizes, int n_in,
                              void* d_out, int out_size, void* d_ws, size_t ws_size,
                              hipStream_t stream) {
    const float* x      = (const float*)d_in[0];
    const float* W_in   = (const float*)d_in[1];
    const float* b_in   = (const float*)d_in[2];
    const float* W_h    = (const float*)d_in[3];
    const float* b_h    = (const float*)d_in[4];
    const float* W_psqt = (const float*)d_in[5];
    float* out = (float*)d_out;

    float* amax = (float*)d_ws;
    float* part = (float*)((char*)d_ws + 64);
    signed char* Wq = (signed char*)d_ws + WQ_OFF;      // 768 KB

    amax_stage1<<<256, 256, 0, stream>>>(W_in, part);
    amax_stage2<<<1, 256, 0, stream>>>(part, amax);
    quant_k<<<768, 256, 0, stream>>>(W_in, amax, (u32*)Wq);

    int B = out_size;                   // 65536
    nnue_fwd<<<B / 64, 512, 0, stream>>>(x, Wq, amax, b_in, W_h, b_h,
                                         W_psqt, out);
}

// Round 5
// 105.651 us; speedup vs baseline: 1.5860x; 1.5860x over previous
//
#include <hip/hip_runtime.h>

typedef unsigned int u32;
typedef unsigned short u16;
typedef unsigned char u8;
typedef int i32x4 __attribute__((ext_vector_type(4)));
typedef int i32x16 __attribute__((ext_vector_type(16)));

// ws layout (bytes):
//   [0..3]      amax (float)
//   [64..1087]  256 partial maxima (float)
//   [2048..]    Wq: [1024 n][768 k] signed int8 (same layout as W_in)
#define WQ_OFF 2048

#define RFL(x) __builtin_amdgcn_readfirstlane(x)

__device__ __forceinline__ void gld16(const void* g, void* l) {
    __builtin_amdgcn_global_load_lds(
        (const __attribute__((address_space(1))) void*)g,
        (__attribute__((address_space(3))) void*)l, 16, 0, 0);
}

// ---------------------------------------------------------------------------
// absmax two-stage tree (no atomics)
// ---------------------------------------------------------------------------
__global__ __launch_bounds__(256) void amax_stage1(const float* __restrict__ W,
                                                   float* __restrict__ part) {
    int t = blockIdx.x * 256 + threadIdx.x;
    float v = 0.0f;
#pragma unroll
    for (int k = 0; k < 12; ++k) v = fmaxf(v, fabsf(W[t + (k << 16)]));
#pragma unroll
    for (int d = 32; d >= 1; d >>= 1) v = fmaxf(v, __shfl_xor(v, d));
    __shared__ float sm[4];
    if ((threadIdx.x & 63) == 0) sm[threadIdx.x >> 6] = v;
    __syncthreads();
    if (threadIdx.x == 0)
        part[blockIdx.x] = fmaxf(fmaxf(sm[0], sm[1]), fmaxf(sm[2], sm[3]));
}

__global__ __launch_bounds__(256) void amax_stage2(const float* __restrict__ part,
                                                   float* __restrict__ amax) {
    float v = part[threadIdx.x];
#pragma unroll
    for (int d = 32; d >= 1; d >>= 1) v = fmaxf(v, __shfl_xor(v, d));
    __shared__ float sm[4];
    if ((threadIdx.x & 63) == 0) sm[threadIdx.x >> 6] = v;
    __syncthreads();
    if (threadIdx.x == 0)
        amax[0] = fmaxf(fmaxf(sm[0], sm[1]), fmaxf(sm[2], sm[3]));
}

// ---------------------------------------------------------------------------
// quantize W_in -> signed i8, same [1024][768] layout
// ---------------------------------------------------------------------------
__global__ __launch_bounds__(256) void quant_k(const float* __restrict__ W,
                                               const float* __restrict__ amax,
                                               u32* __restrict__ Wq4) {
    int i = blockIdx.x * 256 + threadIdx.x;     // dword index, 196608 total
    float s = 127.0f / amax[0];
    float4 v = ((const float4*)W)[i];
    int a0 = (int)rintf(v.x * s), a1 = (int)rintf(v.y * s);
    int a2 = (int)rintf(v.z * s), a3 = (int)rintf(v.w * s);
    Wq4[i] = (u32)(a0 & 0xFF) | ((u32)(a1 & 0xFF) << 8) |
             ((u32)(a2 & 0xFF) << 16) | ((u32)(a3 & 0xFF) << 24);
}

// ---------------------------------------------------------------------------
// Fused forward. 256 rows/block, 256 blocks (one per CU, single round).
// 8 waves = eight 32-row strips. mfma_i32_32x32x32_i8.
// A (x as i8) lives in 96 VGPRs/lane, loaded in fragment order from global.
// B chunk (64 cols x K=768) staged in LDS [48 kc][64 col][16B] = 48 KB.
// ---------------------------------------------------------------------------
__global__ __launch_bounds__(512, 2) void nnue_fwd(
    const float* __restrict__ x,       // [B][768], values in {0,1}
    const signed char* __restrict__ Wq,// [1024][768] i8
    const float* __restrict__ amax,
    const float* __restrict__ b_in,    // [1024]
    const float* __restrict__ W_h,     // [8][1024]
    const float* __restrict__ b_h,     // [8]
    const float* __restrict__ W_psqt,  // [768]
    float* __restrict__ out) {         // [B]

    __shared__ __align__(16) signed char bs8[48 * 1024];   // [kc][col][16B]
    __shared__ int   bmeta[256];
    __shared__ float pmeta[256];

    const int t = threadIdx.x;
    const int l = t & 63, w = t >> 6;
    const int cl = l & 31;              // col-lane / row-in-strip
    const int hi = l >> 5;              // K-half selector
    const size_t row0 = (size_t)blockIdx.x << 8;
    const int r = (w << 5) + cl;        // this lane's A row (0..255)

    // ---- stage B chunk 0 early (latency hides under the A phase) --------
#define STAGE(c)                                                            \
    _Pragma("unroll")                                                       \
    for (int i = 0; i < 6; ++i)                                             \
        gld16(Wq + (size_t)(((c) << 6) + l) * 768 + (((i << 3) + w) << 4),  \
              &bs8[(i << 13) + (w << 10)]);
    STAGE(0)

    // ---- A: load x in fragment order, pack to i8, popcount + psqt -------
    i32x4 A[24];
    u32 csum = 0;
    float ps = 0.0f;
    {
        const float4* xr = (const float4*)(x + (row0 + r) * 768);
        const float4* pw = (const float4*)W_psqt;
#define PKB(f) ((__float_as_uint(f.x) >> 29)         |                      \
                ((__float_as_uint(f.y) >> 29) << 8)  |                      \
                ((__float_as_uint(f.z) >> 29) << 16) |                      \
                ((__float_as_uint(f.w) >> 29) << 24))
#define DOT4(f, q) ps = fmaf(f.x, q.x, ps); ps = fmaf(f.y, q.y, ps);        \
                   ps = fmaf(f.z, q.z, ps); ps = fmaf(f.w, q.w, ps);
#pragma unroll
        for (int ks = 0; ks < 24; ++ks) {
            int q4 = (ks << 3) + (hi << 2);     // k = ks*32 + hi*16
            float4 f0 = xr[q4 + 0], f1 = xr[q4 + 1];
            float4 f2 = xr[q4 + 2], f3 = xr[q4 + 3];
            float4 p0 = pw[q4 + 0], p1 = pw[q4 + 1];
            float4 p2 = pw[q4 + 2], p3 = pw[q4 + 3];
            u32 d0 = PKB(f0), d1 = PKB(f1), d2 = PKB(f2), d3 = PKB(f3);
            csum += d0 + d1 + d2 + d3;          // byte-lane sums <= 96
            DOT4(f0, p0) DOT4(f1, p1) DOT4(f2, p2) DOT4(f3, p3)
            A[ks] = (i32x4){(int)d0, (int)d1, (int)d2, (int)d3};
        }
#undef DOT4
#undef PKB
    }
    int cnt = (csum & 0xFF) + ((csum >> 8) & 0xFF) +
              ((csum >> 16) & 0xFF) + (csum >> 24);
    cnt += __shfl_xor(cnt, 32);                 // pair (l, l^32) = full row
    ps  += __shfl_xor(ps, 32);
    if (hi == 0) {                              // intra-wave meta (own strip)
        bmeta[r] = (cnt - 1) >> 2;
        pmeta[r] = ps;
    }

    // per-lane epilogue row table: row_in_strip = (g&3) + 8*(g>>2) + 4*hi
    int whoff[16];
#pragma unroll
    for (int g = 0; g < 16; ++g) {
        int er = (w << 5) + (g & 3) + ((g >> 2) << 3) + (hi << 2);
        whoff[g] = bmeta[er] << 10;             // bucket*1024
    }

    const float sc = amax[0] * (1.0f / 127.0f);
    float rs[16];
#pragma unroll
    for (int g = 0; g < 16; ++g) rs[g] = 0.0f;

    __syncthreads();        // drains vmcnt(0): B chunk 0 ready; meta visible

    // ---- main loop: 16 chunks of 64 cols --------------------------------
    for (int c = 0; c < 16; ++c) {
        i32x16 acc0 = {0,0,0,0,0,0,0,0,0,0,0,0,0,0,0,0};
        i32x16 acc1 = {0,0,0,0,0,0,0,0,0,0,0,0,0,0,0,0};
#pragma unroll
        for (int ks = 0; ks < 24; ++ks) {
            const int kc = (ks << 1) + hi;
            const signed char* bp = &bs8[(kc << 10) + (cl << 4)];
            i32x4 b0 = *(const i32x4*)(bp);
            i32x4 b1 = *(const i32x4*)(bp + 512);
            acc0 = __builtin_amdgcn_mfma_i32_32x32x32_i8(A[ks], b0, acc0, 0, 0, 0);
            acc1 = __builtin_amdgcn_mfma_i32_32x32x32_i8(A[ks], b1, acc1, 0, 0, 0);
        }

        // fused epilogue for this chunk (acc -> h -> bucket-head dot)
        const int col0 = (c << 6) + cl;
        const float bi0 = b_in[col0], bi1 = b_in[col0 + 32];
#pragma unroll
        for (int g = 0; g < 16; ++g) {
            float h0 = fminf(fmaxf(fmaf((float)acc0[g], sc, bi0), 0.f), 1.f);
            float h1 = fminf(fmaxf(fmaf((float)acc1[g], sc, bi1), 0.f), 1.f);
            rs[g] = fmaf(h0, W_h[whoff[g] + col0], rs[g]);
            rs[g] = fmaf(h1, W_h[whoff[g] + col0 + 32], rs[g]);
        }

        if (c < 15) {
            __syncthreads();        // all waves done reading bs8
            STAGE(c + 1)
            __syncthreads();        // vmcnt(0) drain: next chunk ready
        }
    }
#undef STAGE

    // ---- reduce over 32 col-lanes, write output -------------------------
#pragma unroll
    for (int g = 0; g < 16; ++g) {
#pragma unroll
        for (int d = 1; d < 32; d <<= 1) rs[g] += __shfl_xor(rs[g], d);
    }
    if (cl == 0) {
#pragma unroll
        for (int g = 0; g < 16; ++g) {
            int er = (w << 5) + (g & 3) + ((g >> 2) << 3) + (hi << 2);
            out[row0 + er] = rs[g] + pmeta[er] + b_h[whoff[g] >> 10];
        }
    }
}

extern "C" void kernel_launch(void* const* d_in, const int* in_sizes, int n_in,
                              void* d_out, int out_size, void* d_ws, size_t ws_size,
                              hipStream_t stream) {
    const float* x      = (const float*)d_in[0];
    const float* W_in   = (const float*)d_in[1];
    const float* b_in   = (const float*)d_in[2];
    const float* W_h    = (const float*)d_in[3];
    const float* b_h    = (const float*)d_in[4];
    const float* W_psqt = (const float*)d_in[5];
    float* out = (float*)d_out;

    float* amax = (float*)d_ws;
    float* part = (float*)((char*)d_ws + 64);
    signed char* Wq = (signed char*)d_ws + WQ_OFF;      // 768 KB

    amax_stage1<<<256, 256, 0, stream>>>(W_in, part);
    amax_stage2<<<1, 256, 0, stream>>>(part, amax);
    quant_k<<<768, 256, 0, stream>>>(W_in, amax, (u32*)Wq);

    int B = out_size;                   // 65536
    nnue_fwd<<<B / 256, 512, 0, stream>>>(x, Wq, amax, b_in, W_h, b_h,
                                          W_psqt, out);
}